// Round 3
// baseline (8942.989 us; speedup 1.0000x reference)
//
// BiLSTM tagger — MI355X. Round 3: k_scan — weights in registers.
// Change log vs R2: (1) k_scan retiled: wave w owns gate w; whh fragments held
// in 128 VGPRs/lane loaded ONCE (were re-read 512 KB/step from LDS -> 2.6us of
// LDS pipe + 1.7e7 bank-conflict cycles). LDS now only a 32KB swizzled f32
// gate-exchange. (2) barrier: per-block flag stores + 64-lane poll (removes
// 16-way RMW serialization at MALL). (3) k_convw vectorized x8.
#include <hip/hip_runtime.h>

typedef unsigned short u16;
typedef unsigned long long ull;
typedef short short8 __attribute__((ext_vector_type(8)));
typedef float float4_ __attribute__((ext_vector_type(4)));
typedef short8 short8a __attribute__((may_alias));
typedef ull ulla __attribute__((may_alias));

#define MFMA16(a, b, c) __builtin_amdgcn_mfma_f32_16x16x32_bf16((a), (b), (c), 0, 0, 0)

static __device__ __forceinline__ float b2f(u16 v) { return __uint_as_float(((unsigned)v) << 16); }
static __device__ __forceinline__ u16 f2b(float f) {
  unsigned x = __float_as_uint(f);
  return (u16)((x + 0x7fffu + ((x >> 16) & 1u)) >> 16);
}
static __device__ __forceinline__ float ldv(const void* p, long long i, int isbf) {
  return isbf ? b2f(((const u16*)p)[i]) : ((const float*)p)[i];
}
static __device__ __forceinline__ float sigm(float x) { return 1.f / (1.f + __expf(-x)); }
static __device__ __forceinline__ float tanh_(float x) { return 1.f - 2.f / (__expf(2.f * x) + 1.f); }
static __device__ __forceinline__ float4_ splat4(float v) { float4_ r; r[0]=v; r[1]=v; r[2]=v; r[3]=v; return r; }

// ---------------- dtype detection (f32 vs bf16 input buffers) ----------------
__global__ __launch_bounds__(256) void k_detect(const unsigned* __restrict__ wtag, int* __restrict__ flag) {
  __shared__ int cs;
  if (threadIdx.x == 0) cs = 0;
  __syncthreads();
  int hits = 0;
  for (int i = threadIdx.x; i < 1024; i += 256) {
    unsigned b = (wtag[i] >> 8) & 0x7fu;
    hits += (b >= 0x36u && b <= 0x3fu) ? 1 : 0;
  }
  atomicAdd(&cs, hits);
  __syncthreads();
  if (threadIdx.x == 0) *flag = (cs > 512) ? 1 : 0;
}

// ---------------- weight conversion to bf16 workspace (x8 vectorized) ----------------
// All segment boundaries are multiples of 8, so an aligned 8-group never crosses.
struct WSegs { const void* src[15]; int dst[15]; int n[15]; };
__global__ __launch_bounds__(256) void k_convw(WSegs s, u16* __restrict__ wt, const int* __restrict__ flagp) {
  const int isbf = *flagp;
  const long long total8 = 9830400 / 8;
  for (long long i8 = (long long)blockIdx.x * 256 + threadIdx.x; i8 < total8; i8 += (long long)gridDim.x * 256) {
    const long long i = i8 * 8;
    int k = 0;
#pragma unroll
    for (int j = 1; j < 15; ++j) if (i >= (long long)s.dst[j]) k = j;
    const long long loc = i - s.dst[k];
    short8 out;
    if (!s.src[k]) {
      for (int j = 0; j < 8; ++j) out[j] = 0;
    } else if (isbf) {
      out = *(const short8a*)((const u16*)s.src[k] + loc);
    } else {
      const float* fp = (const float*)s.src[k] + loc;
      const float4_ f0 = *(const float4_*)fp;
      const float4_ f1 = *(const float4_*)(fp + 4);
#pragma unroll
      for (int j = 0; j < 4; ++j) { out[j] = (short)f2b(f0[j]); out[j + 4] = (short)f2b(f1[j]); }
    }
    *(short8a*)(wt + i) = out;
  }
}

struct BSegs { const void* a[8]; const void* b[8]; int dst[8]; int n[8]; int np[8]; };
__global__ __launch_bounds__(256) void k_convb(BSegs s, float* __restrict__ bias, const int* __restrict__ flagp) {
  const int isbf = *flagp;
  for (int i = blockIdx.x * 256 + threadIdx.x; i < 9536; i += gridDim.x * 256) {
    int k = 0;
#pragma unroll
    for (int j = 1; j < 8; ++j) if (i >= s.dst[j]) k = j;
    const int loc = i - s.dst[k];
    float v = 0.f;
    if (loc < s.n[k]) {
      v = ldv(s.a[k], loc, isbf);
      if (s.b[k]) v += ldv(s.b[k], loc, isbf);
    }
    bias[i] = v;
  }
}

// ---------------- word embedding gather into cat[:,0:256] ----------------
__global__ __launch_bounds__(128) void k_wordgather(const int* __restrict__ sent, const void* __restrict__ wemb,
                                                    u16* __restrict__ cat, const int* __restrict__ flagp) {
  const int n = blockIdx.x;
  const int idx = sent[n];
  const int isbf = *flagp;
  for (int d = threadIdx.x; d < 256; d += 128)
    cat[(long long)n * 512 + d] = f2b(ldv(wemb, (long long)idx * 256 + d, isbf));
}

// ---------------- char biLSTM: 64 seqs/block, 16 steps, D=64 H=128 ----------------
__global__ __launch_bounds__(256) void k_char(const int* __restrict__ cs, const void* __restrict__ wchar,
                                              const u16* __restrict__ wihF, const u16* __restrict__ whhF,
                                              const u16* __restrict__ wihB, const u16* __restrict__ whhB,
                                              const float* __restrict__ biasF, const float* __restrict__ biasB,
                                              u16* __restrict__ cat, const int* __restrict__ flagp) {
  const int dir = blockIdx.y;
  const int nb = blockIdx.x;
  const u16* wih = dir ? wihB : wihF;
  const u16* whh = dir ? whhB : whhF;
  const float* bias = dir ? biasB : biasF;
  const int isbf = *flagp;
  __shared__ __align__(16) u16 xs[64][72];
  __shared__ __align__(16) u16 hs[64][136];
  const int tid = threadIdx.x, wv = tid >> 6, lane = tid & 63;
  for (int i = tid; i < 64 * 136; i += 256) ((u16*)hs)[i] = 0;
  float c[2][4][4];
#pragma unroll
  for (int a1 = 0; a1 < 2; ++a1)
#pragma unroll
    for (int a2 = 0; a2 < 4; ++a2)
#pragma unroll
      for (int a3 = 0; a3 < 4; ++a3) c[a1][a2][a3] = 0.f;

  for (int tt = 0; tt < 16; ++tt) {
    const int t = dir ? (15 - tt) : tt;
    {
      const int sid = tid >> 2, part = tid & 3;
      const int n = nb * 64 + sid;
      const int idx = cs[n * 16 + t];
#pragma unroll
      for (int q = 0; q < 16; ++q) {
        const int d2 = part * 16 + q;
        float v = 0.f;
        if (idx != 0) v = ldv(wchar, (long long)idx * 64 + d2, isbf);
        xs[sid][d2] = f2b(v);
      }
    }
    __syncthreads();
    float4_ acc[2][4][4];
#pragma unroll
    for (int ut = 0; ut < 2; ++ut)
#pragma unroll
      for (int g = 0; g < 4; ++g) {
        const float bv = bias[g * 128 + (wv + 4 * ut) * 16 + (lane & 15)];
#pragma unroll
        for (int rt = 0; rt < 4; ++rt) acc[ut][g][rt] = splat4(bv);
      }
#pragma unroll
    for (int kc = 0; kc < 6; ++kc) {
      short8 a[4];
      if (kc < 2) {
#pragma unroll
        for (int rt = 0; rt < 4; ++rt)
          a[rt] = *(const short8a*)&xs[rt * 16 + (lane & 15)][kc * 32 + (lane >> 4) * 8];
      } else {
#pragma unroll
        for (int rt = 0; rt < 4; ++rt)
          a[rt] = *(const short8a*)&hs[rt * 16 + (lane & 15)][(kc - 2) * 32 + (lane >> 4) * 8];
      }
#pragma unroll
      for (int ut = 0; ut < 2; ++ut)
#pragma unroll
        for (int g = 0; g < 4; ++g) {
          const int col = g * 128 + (wv + 4 * ut) * 16 + (lane & 15);
          short8 bfr;
          if (kc < 2) bfr = *(const short8a*)(wih + col * 64 + kc * 32 + (lane >> 4) * 8);
          else        bfr = *(const short8a*)(whh + col * 128 + (kc - 2) * 32 + (lane >> 4) * 8);
#pragma unroll
          for (int rt = 0; rt < 4; ++rt) acc[ut][g][rt] = MFMA16(a[rt], bfr, acc[ut][g][rt]);
        }
    }
    __syncthreads();
#pragma unroll
    for (int ut = 0; ut < 2; ++ut)
#pragma unroll
      for (int rt = 0; rt < 4; ++rt)
#pragma unroll
        for (int r = 0; r < 4; ++r) {
          const float iv = acc[ut][0][rt][r];
          const float fv = acc[ut][1][rt][r];
          const float gv = acc[ut][2][rt][r];
          const float ov = acc[ut][3][rt][r];
          float& cc = c[ut][rt][r];
          cc = sigm(fv) * cc + sigm(iv) * tanh_(gv);
          const float h = sigm(ov) * tanh_(cc);
          const int seq = rt * 16 + (lane >> 4) * 4 + r;
          const int u = (wv + 4 * ut) * 16 + (lane & 15);
          const u16 hv = f2b(h);
          hs[seq][u] = hv;
          if (tt == 15) cat[(long long)(nb * 64 + seq) * 512 + 256 + dir * 128 + u] = hv;
        }
  }
}

// ---------------- generic MFMA GEMM ----------------
template <int TM, int TN, int PERM, int OUTM>
__global__ __launch_bounds__(256) void k_gemm(const u16* __restrict__ A, const u16* __restrict__ Wt,
                                              const float* __restrict__ bias, void* __restrict__ Cout,
                                              const int N, const int K, const int ldc,
                                              const int* __restrict__ flagp) {
  constexpr int RT = TM / 16;
  constexpr int CPW = TN / 64;
  const int bm = blockIdx.x, bn = blockIdx.y;
  const int tid = threadIdx.x, wv = tid >> 6, lane = tid & 63;
  __shared__ __align__(16) u16 As[TM][72];
  float4_ acc[CPW][RT];
#pragma unroll
  for (int ci = 0; ci < CPW; ++ci)
#pragma unroll
    for (int rt = 0; rt < RT; ++rt) acc[ci][rt] = splat4(0.f);
  const int nk = K >> 6;
  for (int kc = 0; kc < nk; ++kc) {
    __syncthreads();
    for (int idx = tid; idx < TM * 4; idx += 256) {
      const int r = idx >> 2, sg = idx & 3;
      const u16* src = A + (long long)(bm * TM + r) * K + kc * 64 + sg * 16;
      *(short8a*)&As[r][sg * 16] = *(const short8a*)src;
      *(short8a*)&As[r][sg * 16 + 8] = *(const short8a*)(src + 8);
    }
    __syncthreads();
#pragma unroll
    for (int kk = 0; kk < 2; ++kk) {
      short8 af[RT];
#pragma unroll
      for (int rt = 0; rt < RT; ++rt)
        af[rt] = *(const short8a*)&As[rt * 16 + (lane & 15)][kk * 32 + (lane >> 4) * 8];
#pragma unroll
      for (int ci = 0; ci < CPW; ++ci) {
        const int ct = wv + ci * 4;
        const short8 bf = *(const short8a*)(Wt + (long long)(bn * TN + ct * 16 + (lane & 15)) * K +
                                            kc * 64 + kk * 32 + (lane >> 4) * 8);
#pragma unroll
        for (int rt = 0; rt < RT; ++rt) acc[ci][rt] = MFMA16(af[rt], bf, acc[ci][rt]);
      }
    }
  }
  const int isbf = (OUTM == 1) ? *flagp : 0;
#pragma unroll
  for (int ci = 0; ci < CPW; ++ci)
#pragma unroll
    for (int rt = 0; rt < RT; ++rt)
#pragma unroll
      for (int r = 0; r < 4; ++r) {
        const int row = bm * TM + rt * 16 + (lane >> 4) * 4 + r;
        const int col = bn * TN + (wv + ci * 4) * 16 + (lane & 15);
        if (col < N) {
          const float v = acc[ci][rt][r] + bias[col];
          long long orow;
          if (PERM == 0) orow = row;
          else if (PERM == 1) orow = (long long)(row & 255) * 64 + (row >> 8);
          else orow = (long long)(row & 63) * 256 + (row >> 6);
          if (OUTM == 0) ((u16*)Cout)[orow * ldc + col] = f2b(v);
          else if (isbf) ((u16*)Cout)[orow * ldc + col] = f2b(v);
          else ((float*)Cout)[orow * ldc + col] = v;
        }
      }
}

// ---------------- persistent LSTM scan (one layer, both dirs) ----------------
// grid (16, 2=dir). Block owns 32 hidden units. Wave w owns GATE w: whh
// fragments for (2 unit-tiles x 16 kc) live in registers, loaded once.
// Per step: h loaded from global (L1-shared by 4 waves), 128 MFMA/wave into
// f32 gate-exchange LDS (32KB, swizzled), per-thread activation of 8 outputs,
// u64 write-through h publish, per-block flag + 64-lane poll + one acq fence.
__global__ __launch_bounds__(256, 1) void k_scan(const u16* __restrict__ pre0, const u16* __restrict__ pre1,
                                                 const u16* __restrict__ whh0, const u16* __restrict__ whh1,
                                                 u16* __restrict__ o_out, u16* __restrict__ hbuf,
                                                 int* __restrict__ flags) {
  const int dir = blockIdx.y, blk = blockIdx.x;
  const u16* __restrict__ pre = dir ? pre1 : pre0;
  const u16* __restrict__ whh = dir ? whh1 : whh0;
  u16* hb = hbuf + dir * (2 * 64 * 512);
  int* myflags = flags + dir * 16;
  const int u0 = blk * 32;
  __shared__ __align__(16) float xch[64 * 128];  // byte-addressed with XOR swizzle
  const int tid = threadIdx.x, wv = tid >> 6, lane = tid & 63;
  const int l15 = lane & 15, q = lane >> 4;

  // persistent weight fragments: gate = wv, rows u0 + ci*16 + l15, k = kc*32+q*8
  short8 sw[2][16];
#pragma unroll
  for (int ci = 0; ci < 2; ++ci)
#pragma unroll
    for (int kc = 0; kc < 16; ++kc)
      sw[ci][kc] = *(const short8a*)(whh + (long long)(wv * 512 + u0 + ci * 16 + l15) * 512 + kc * 32 + q * 8);

  // activation ownership: batch ab, unit octet u0+au .. +8
  const int ab = tid >> 2;
  const int au = (tid & 3) * 8;
  float c8[8];
#pragma unroll
  for (int j = 0; j < 8; ++j) c8[j] = 0.f;

  short8 pr[4], prn[4];
  {
    const int t0 = dir ? 255 : 0;
#pragma unroll
    for (int g = 0; g < 4; ++g)
      pr[g] = *(const short8a*)(pre + (long long)(t0 * 64 + ab) * 2048 + g * 512 + u0 + au);
  }

  for (int tt = 0; tt < 256; ++tt) {
    const int t = dir ? (255 - tt) : tt;
    const u16* hrd = hb + (tt & 1) * 32768;
    u16* hwr = hb + ((tt + 1) & 1) * 32768;

    float4_ acc[2][4];
#pragma unroll
    for (int ci = 0; ci < 2; ++ci)
#pragma unroll
      for (int bt = 0; bt < 4; ++bt) acc[ci][bt] = splat4(0.f);
#pragma unroll 4
    for (int kc = 0; kc < 16; ++kc) {
      short8 a[4];
#pragma unroll
      for (int bt = 0; bt < 4; ++bt)
        a[bt] = *(const short8a*)(hrd + (bt * 16 + l15) * 512 + kc * 32 + q * 8);
#pragma unroll
      for (int ci = 0; ci < 2; ++ci)
#pragma unroll
        for (int bt = 0; bt < 4; ++bt)
          acc[ci][bt] = MFMA16(sw[ci][kc], a[bt], acc[ci][bt]);  // row=unit(gate wv), col=batch
    }
    // gate exchange: write acc, swizzled (conflict-free b128)
#pragma unroll
    for (int ci = 0; ci < 2; ++ci)
#pragma unroll
      for (int bt = 0; bt < 4; ++bt) {
        const int b = bt * 16 + l15;
        const int lrb = wv * 32 + ci * 16 + q * 4;
        *(float4_*)((char*)xch + b * 512 + ((lrb * 4) ^ ((b & 3) << 6))) = acc[ci][bt];
      }
    __syncthreads();
    float4_ gv[4][2];
#pragma unroll
    for (int g = 0; g < 4; ++g)
#pragma unroll
      for (int h2 = 0; h2 < 2; ++h2) {
        const int lr = g * 32 + au + h2 * 4;
        gv[g][h2] = *(const float4_*)((const char*)xch + ab * 512 + ((lr * 4) ^ ((ab & 3) << 6)));
      }
    ull hv[2]; hv[0] = 0; hv[1] = 0;
#pragma unroll
    for (int j = 0; j < 8; ++j) {
      const float iv = gv[0][j >> 2][j & 3] + b2f((u16)pr[0][j]);
      const float fv = gv[1][j >> 2][j & 3] + b2f((u16)pr[1][j]);
      const float gg = gv[2][j >> 2][j & 3] + b2f((u16)pr[2][j]);
      const float ov = gv[3][j >> 2][j & 3] + b2f((u16)pr[3][j]);
      c8[j] = sigm(fv) * c8[j] + sigm(iv) * tanh_(gg);
      const float h = sigm(ov) * tanh_(c8[j]);
      hv[j >> 2] |= (ull)f2b(h) << (16 * (j & 3));
    }
#pragma unroll
    for (int p = 0; p < 2; ++p)
      __hip_atomic_store((ull*)(hwr + ab * 512 + u0 + au) + p, hv[p],
                         __ATOMIC_RELAXED, __HIP_MEMORY_SCOPE_AGENT);
    asm volatile("s_waitcnt vmcnt(0)" ::: "memory");  // h at coherent point
    __syncthreads();
    if (tid == 0)
      __hip_atomic_store(&myflags[blk], tt + 1, __ATOMIC_RELAXED, __HIP_MEMORY_SCOPE_AGENT);
    // overlap the wait: o_out store + next-step pre prefetch
    {
      ull* op = (ull*)(o_out + (long long)(t * 64 + ab) * 1024 + dir * 512 + u0 + au);
      op[0] = hv[0]; op[1] = hv[1];
    }
    {
      const int ttn = (tt < 255) ? tt + 1 : tt;
      const int tn = dir ? (255 - ttn) : ttn;
#pragma unroll
      for (int g = 0; g < 4; ++g)
        prn[g] = *(const short8a*)(pre + (long long)(tn * 64 + ab) * 2048 + g * 512 + u0 + au);
    }
    if (tt != 255) {
      if (wv == 0) {
        int v;
        do {
          v = __hip_atomic_load(&myflags[l15], __ATOMIC_RELAXED, __HIP_MEMORY_SCOPE_AGENT);
        } while (__all(v >= tt + 1) == 0);
      }
      __syncthreads();
      __builtin_amdgcn_fence(__ATOMIC_ACQUIRE, "agent");  // one inv; fresh h loads
    }
#pragma unroll
    for (int g = 0; g < 4; ++g) pr[g] = prn[g];
  }
}

// ---------------- launcher ----------------
static constexpr long long OFF_WT = 0;
static constexpr long long OFF_BIAS = 19660800;
static constexpr long long OFF_CAT = 19698944;
static constexpr long long OFF_EMB = 36476160;
static constexpr long long OFF_PRE = 44864768;
static constexpr long long OFF_O1 = 179082496;
static constexpr long long OFF_O2 = 212636928;
static constexpr long long OFF_SYNC = 246191360;
static constexpr long long SYNC_BYTES = 4096 + 524288;
static constexpr long long OFF_FLAG = OFF_SYNC + SYNC_BYTES;

extern "C" void kernel_launch(void* const* d_in, const int* in_sizes, int n_in,
                              void* d_out, int out_size, void* d_ws, size_t ws_size,
                              hipStream_t stream) {
  char* ws = (char*)d_ws;
  u16* wt = (u16*)(ws + OFF_WT);
  float* biasp = (float*)(ws + OFF_BIAS);
  u16* cat = (u16*)(ws + OFF_CAT);
  u16* emb = (u16*)(ws + OFF_EMB);
  u16* pre0 = (u16*)(ws + OFF_PRE);
  u16* pre1 = pre0 + (long long)16384 * 2048;
  u16* o1 = (u16*)(ws + OFF_O1);
  u16* o2 = (u16*)(ws + OFF_O2);
  int* cnt1 = (int*)(ws + OFF_SYNC);
  int* cnt2 = cnt1 + 512;
  u16* h1 = (u16*)(ws + OFF_SYNC + 4096);
  u16* h2 = h1 + 131072;
  int* flag = (int*)(ws + OFF_FLAG);

  hipMemsetAsync(ws + OFF_SYNC, 0, SYNC_BYTES, stream);
  k_detect<<<1, 256, 0, stream>>>((const unsigned*)d_in[30], flag);

  WSegs wsg;
  const int widx[14] = {4, 5, 8, 9, 12, 13, 16, 17, 20, 21, 24, 25, 28, 30};
  const int wdst[15] = {0, 32768, 98304, 131072, 196608, 720896, 1769472, 2293760,
                        3342336, 5439488, 6488064, 8585216, 9633792, 9764864, 9816064};
  const int wn[15] = {32768, 65536, 32768, 65536, 524288, 1048576, 524288, 1048576,
                      2097152, 1048576, 2097152, 1048576, 131072, 51200, 14336};
  for (int j = 0; j < 14; ++j) { wsg.src[j] = d_in[widx[j]]; wsg.dst[j] = wdst[j]; wsg.n[j] = wn[j]; }
  wsg.src[14] = nullptr; wsg.dst[14] = wdst[14]; wsg.n[14] = wn[14];
  k_convw<<<1200, 256, 0, stream>>>(wsg, wt, flag);

  BSegs bsg;
  const int ba[8] = {6, 10, 14, 18, 22, 26, 29, 31};
  const int bb[8] = {7, 11, 15, 19, 23, 27, -1, -1};
  const int bdst[8] = {0, 512, 1024, 3072, 5120, 7168, 9216, 9472};
  const int bn_[8] = {512, 512, 2048, 2048, 2048, 2048, 256, 50};
  const int bnp[8] = {512, 512, 2048, 2048, 2048, 2048, 256, 64};
  for (int j = 0; j < 8; ++j) {
    bsg.a[j] = d_in[ba[j]];
    bsg.b[j] = (bb[j] >= 0) ? d_in[bb[j]] : nullptr;
    bsg.dst[j] = bdst[j]; bsg.n[j] = bn_[j]; bsg.np[j] = bnp[j];
  }
  k_convb<<<40, 256, 0, stream>>>(bsg, biasp, flag);

  k_wordgather<<<16384, 128, 0, stream>>>((const int*)d_in[0], d_in[2], cat, flag);
  k_char<<<dim3(256, 2), 256, 0, stream>>>((const int*)d_in[1], d_in[3],
                                           wt + 0, wt + 32768, wt + 98304, wt + 131072,
                                           biasp + 0, biasp + 512, cat, flag);
  k_gemm<64, 64, 1, 0><<<dim3(256, 4), 256, 0, stream>>>(cat, wt + 9633792, biasp + 9216, emb, 256, 512, 256, flag);
  k_gemm<128, 256, 0, 0><<<dim3(128, 8), 256, 0, stream>>>(emb, wt + 196608, biasp + 1024, pre0, 2048, 256, 2048, flag);
  k_gemm<128, 256, 0, 0><<<dim3(128, 8), 256, 0, stream>>>(emb, wt + 1769472, biasp + 3072, pre1, 2048, 256, 2048, flag);
  k_scan<<<dim3(16, 2), 256, 0, stream>>>(pre0, pre1, wt + 720896, wt + 2293760, o1, h1, cnt1);
  k_gemm<128, 256, 0, 0><<<dim3(128, 8), 256, 0, stream>>>(o1, wt + 3342336, biasp + 5120, pre0, 2048, 1024, 2048, flag);
  k_gemm<128, 256, 0, 0><<<dim3(128, 8), 256, 0, stream>>>(o1, wt + 6488064, biasp + 7168, pre1, 2048, 1024, 2048, flag);
  k_scan<<<dim3(16, 2), 256, 0, stream>>>(pre0, pre1, wt + 5439488, wt + 8585216, o2, h2, cnt2);
  k_gemm<64, 64, 2, 1><<<dim3(256, 1), 256, 0, stream>>>(o2, wt + 9764864, biasp + 9472, d_out, 50, 1024, 50, flag);
}

// Round 4
// 6570.911 us; speedup vs baseline: 1.3610x; 1.3610x over previous
//
// BiLSTM tagger — MI355X. Round 4: fix R3's scratch-spilled weights.
// Change log vs R3: (1) kc loop FULLY unrolled -> sw[2][16] statically indexed
// and truly register-resident (R3's "#pragma unroll 4" left runtime indexing
// -> scratch, VGPR_Count=104 proved it). (2) h loads via per-bt base pointers
// + literal offsets. (3) s_sleep(1) in flag poll (73ms outlier was MALL
// starvation from sleepless polling). (4) exchange swizzle (b&7)<<6 both sides.
#include <hip/hip_runtime.h>

typedef unsigned short u16;
typedef unsigned long long ull;
typedef short short8 __attribute__((ext_vector_type(8)));
typedef float float4_ __attribute__((ext_vector_type(4)));
typedef short8 short8a __attribute__((may_alias));
typedef ull ulla __attribute__((may_alias));

#define MFMA16(a, b, c) __builtin_amdgcn_mfma_f32_16x16x32_bf16((a), (b), (c), 0, 0, 0)

static __device__ __forceinline__ float b2f(u16 v) { return __uint_as_float(((unsigned)v) << 16); }
static __device__ __forceinline__ u16 f2b(float f) {
  unsigned x = __float_as_uint(f);
  return (u16)((x + 0x7fffu + ((x >> 16) & 1u)) >> 16);
}
static __device__ __forceinline__ float ldv(const void* p, long long i, int isbf) {
  return isbf ? b2f(((const u16*)p)[i]) : ((const float*)p)[i];
}
static __device__ __forceinline__ float sigm(float x) { return 1.f / (1.f + __expf(-x)); }
static __device__ __forceinline__ float tanh_(float x) { return 1.f - 2.f / (__expf(2.f * x) + 1.f); }
static __device__ __forceinline__ float4_ splat4(float v) { float4_ r; r[0]=v; r[1]=v; r[2]=v; r[3]=v; return r; }

// ---------------- dtype detection (f32 vs bf16 input buffers) ----------------
__global__ __launch_bounds__(256) void k_detect(const unsigned* __restrict__ wtag, int* __restrict__ flag) {
  __shared__ int cs;
  if (threadIdx.x == 0) cs = 0;
  __syncthreads();
  int hits = 0;
  for (int i = threadIdx.x; i < 1024; i += 256) {
    unsigned b = (wtag[i] >> 8) & 0x7fu;
    hits += (b >= 0x36u && b <= 0x3fu) ? 1 : 0;
  }
  atomicAdd(&cs, hits);
  __syncthreads();
  if (threadIdx.x == 0) *flag = (cs > 512) ? 1 : 0;
}

// ---------------- weight conversion to bf16 workspace (x8 vectorized) ----------------
struct WSegs { const void* src[15]; int dst[15]; int n[15]; };
__global__ __launch_bounds__(256) void k_convw(WSegs s, u16* __restrict__ wt, const int* __restrict__ flagp) {
  const int isbf = *flagp;
  const long long total8 = 9830400 / 8;
  for (long long i8 = (long long)blockIdx.x * 256 + threadIdx.x; i8 < total8; i8 += (long long)gridDim.x * 256) {
    const long long i = i8 * 8;
    int k = 0;
#pragma unroll
    for (int j = 1; j < 15; ++j) if (i >= (long long)s.dst[j]) k = j;
    const long long loc = i - s.dst[k];
    short8 out;
    if (!s.src[k]) {
      for (int j = 0; j < 8; ++j) out[j] = 0;
    } else if (isbf) {
      out = *(const short8a*)((const u16*)s.src[k] + loc);
    } else {
      const float* fp = (const float*)s.src[k] + loc;
      const float4_ f0 = *(const float4_*)fp;
      const float4_ f1 = *(const float4_*)(fp + 4);
#pragma unroll
      for (int j = 0; j < 4; ++j) { out[j] = (short)f2b(f0[j]); out[j + 4] = (short)f2b(f1[j]); }
    }
    *(short8a*)(wt + i) = out;
  }
}

struct BSegs { const void* a[8]; const void* b[8]; int dst[8]; int n[8]; int np[8]; };
__global__ __launch_bounds__(256) void k_convb(BSegs s, float* __restrict__ bias, const int* __restrict__ flagp) {
  const int isbf = *flagp;
  for (int i = blockIdx.x * 256 + threadIdx.x; i < 9536; i += gridDim.x * 256) {
    int k = 0;
#pragma unroll
    for (int j = 1; j < 8; ++j) if (i >= s.dst[j]) k = j;
    const int loc = i - s.dst[k];
    float v = 0.f;
    if (loc < s.n[k]) {
      v = ldv(s.a[k], loc, isbf);
      if (s.b[k]) v += ldv(s.b[k], loc, isbf);
    }
    bias[i] = v;
  }
}

// ---------------- word embedding gather into cat[:,0:256] ----------------
__global__ __launch_bounds__(128) void k_wordgather(const int* __restrict__ sent, const void* __restrict__ wemb,
                                                    u16* __restrict__ cat, const int* __restrict__ flagp) {
  const int n = blockIdx.x;
  const int idx = sent[n];
  const int isbf = *flagp;
  for (int d = threadIdx.x; d < 256; d += 128)
    cat[(long long)n * 512 + d] = f2b(ldv(wemb, (long long)idx * 256 + d, isbf));
}

// ---------------- char biLSTM: 64 seqs/block, 16 steps, D=64 H=128 ----------------
__global__ __launch_bounds__(256) void k_char(const int* __restrict__ cs, const void* __restrict__ wchar,
                                              const u16* __restrict__ wihF, const u16* __restrict__ whhF,
                                              const u16* __restrict__ wihB, const u16* __restrict__ whhB,
                                              const float* __restrict__ biasF, const float* __restrict__ biasB,
                                              u16* __restrict__ cat, const int* __restrict__ flagp) {
  const int dir = blockIdx.y;
  const int nb = blockIdx.x;
  const u16* wih = dir ? wihB : wihF;
  const u16* whh = dir ? whhB : whhF;
  const float* bias = dir ? biasB : biasF;
  const int isbf = *flagp;
  __shared__ __align__(16) u16 xs[64][72];
  __shared__ __align__(16) u16 hs[64][136];
  const int tid = threadIdx.x, wv = tid >> 6, lane = tid & 63;
  for (int i = tid; i < 64 * 136; i += 256) ((u16*)hs)[i] = 0;
  float c[2][4][4];
#pragma unroll
  for (int a1 = 0; a1 < 2; ++a1)
#pragma unroll
    for (int a2 = 0; a2 < 4; ++a2)
#pragma unroll
      for (int a3 = 0; a3 < 4; ++a3) c[a1][a2][a3] = 0.f;

  for (int tt = 0; tt < 16; ++tt) {
    const int t = dir ? (15 - tt) : tt;
    {
      const int sid = tid >> 2, part = tid & 3;
      const int n = nb * 64 + sid;
      const int idx = cs[n * 16 + t];
#pragma unroll
      for (int q = 0; q < 16; ++q) {
        const int d2 = part * 16 + q;
        float v = 0.f;
        if (idx != 0) v = ldv(wchar, (long long)idx * 64 + d2, isbf);
        xs[sid][d2] = f2b(v);
      }
    }
    __syncthreads();
    float4_ acc[2][4][4];
#pragma unroll
    for (int ut = 0; ut < 2; ++ut)
#pragma unroll
      for (int g = 0; g < 4; ++g) {
        const float bv = bias[g * 128 + (wv + 4 * ut) * 16 + (lane & 15)];
#pragma unroll
        for (int rt = 0; rt < 4; ++rt) acc[ut][g][rt] = splat4(bv);
      }
#pragma unroll
    for (int kc = 0; kc < 6; ++kc) {
      short8 a[4];
      if (kc < 2) {
#pragma unroll
        for (int rt = 0; rt < 4; ++rt)
          a[rt] = *(const short8a*)&xs[rt * 16 + (lane & 15)][kc * 32 + (lane >> 4) * 8];
      } else {
#pragma unroll
        for (int rt = 0; rt < 4; ++rt)
          a[rt] = *(const short8a*)&hs[rt * 16 + (lane & 15)][(kc - 2) * 32 + (lane >> 4) * 8];
      }
#pragma unroll
      for (int ut = 0; ut < 2; ++ut)
#pragma unroll
        for (int g = 0; g < 4; ++g) {
          const int col = g * 128 + (wv + 4 * ut) * 16 + (lane & 15);
          short8 bfr;
          if (kc < 2) bfr = *(const short8a*)(wih + col * 64 + kc * 32 + (lane >> 4) * 8);
          else        bfr = *(const short8a*)(whh + col * 128 + (kc - 2) * 32 + (lane >> 4) * 8);
#pragma unroll
          for (int rt = 0; rt < 4; ++rt) acc[ut][g][rt] = MFMA16(a[rt], bfr, acc[ut][g][rt]);
        }
    }
    __syncthreads();
#pragma unroll
    for (int ut = 0; ut < 2; ++ut)
#pragma unroll
      for (int rt = 0; rt < 4; ++rt)
#pragma unroll
        for (int r = 0; r < 4; ++r) {
          const float iv = acc[ut][0][rt][r];
          const float fv = acc[ut][1][rt][r];
          const float gv = acc[ut][2][rt][r];
          const float ov = acc[ut][3][rt][r];
          float& cc = c[ut][rt][r];
          cc = sigm(fv) * cc + sigm(iv) * tanh_(gv);
          const float h = sigm(ov) * tanh_(cc);
          const int seq = rt * 16 + (lane >> 4) * 4 + r;
          const int u = (wv + 4 * ut) * 16 + (lane & 15);
          const u16 hv = f2b(h);
          hs[seq][u] = hv;
          if (tt == 15) cat[(long long)(nb * 64 + seq) * 512 + 256 + dir * 128 + u] = hv;
        }
  }
}

// ---------------- generic MFMA GEMM ----------------
template <int TM, int TN, int PERM, int OUTM>
__global__ __launch_bounds__(256) void k_gemm(const u16* __restrict__ A, const u16* __restrict__ Wt,
                                              const float* __restrict__ bias, void* __restrict__ Cout,
                                              const int N, const int K, const int ldc,
                                              const int* __restrict__ flagp) {
  constexpr int RT = TM / 16;
  constexpr int CPW = TN / 64;
  const int bm = blockIdx.x, bn = blockIdx.y;
  const int tid = threadIdx.x, wv = tid >> 6, lane = tid & 63;
  __shared__ __align__(16) u16 As[TM][72];
  float4_ acc[CPW][RT];
#pragma unroll
  for (int ci = 0; ci < CPW; ++ci)
#pragma unroll
    for (int rt = 0; rt < RT; ++rt) acc[ci][rt] = splat4(0.f);
  const int nk = K >> 6;
  for (int kc = 0; kc < nk; ++kc) {
    __syncthreads();
    for (int idx = tid; idx < TM * 4; idx += 256) {
      const int r = idx >> 2, sg = idx & 3;
      const u16* src = A + (long long)(bm * TM + r) * K + kc * 64 + sg * 16;
      *(short8a*)&As[r][sg * 16] = *(const short8a*)src;
      *(short8a*)&As[r][sg * 16 + 8] = *(const short8a*)(src + 8);
    }
    __syncthreads();
#pragma unroll
    for (int kk = 0; kk < 2; ++kk) {
      short8 af[RT];
#pragma unroll
      for (int rt = 0; rt < RT; ++rt)
        af[rt] = *(const short8a*)&As[rt * 16 + (lane & 15)][kk * 32 + (lane >> 4) * 8];
#pragma unroll
      for (int ci = 0; ci < CPW; ++ci) {
        const int ct = wv + ci * 4;
        const short8 bf = *(const short8a*)(Wt + (long long)(bn * TN + ct * 16 + (lane & 15)) * K +
                                            kc * 64 + kk * 32 + (lane >> 4) * 8);
#pragma unroll
        for (int rt = 0; rt < RT; ++rt) acc[ci][rt] = MFMA16(af[rt], bf, acc[ci][rt]);
      }
    }
  }
  const int isbf = (OUTM == 1) ? *flagp : 0;
#pragma unroll
  for (int ci = 0; ci < CPW; ++ci)
#pragma unroll
    for (int rt = 0; rt < RT; ++rt)
#pragma unroll
      for (int r = 0; r < 4; ++r) {
        const int row = bm * TM + rt * 16 + (lane >> 4) * 4 + r;
        const int col = bn * TN + (wv + ci * 4) * 16 + (lane & 15);
        if (col < N) {
          const float v = acc[ci][rt][r] + bias[col];
          long long orow;
          if (PERM == 0) orow = row;
          else if (PERM == 1) orow = (long long)(row & 255) * 64 + (row >> 8);
          else orow = (long long)(row & 63) * 256 + (row >> 6);
          if (OUTM == 0) ((u16*)Cout)[orow * ldc + col] = f2b(v);
          else if (isbf) ((u16*)Cout)[orow * ldc + col] = f2b(v);
          else ((float*)Cout)[orow * ldc + col] = v;
        }
      }
}

// ---------------- persistent LSTM scan (one layer, both dirs) ----------------
// grid (16, 2=dir). Block owns 32 hidden units. Wave w owns GATE w; sw[2][16]
// (32 short8 = 128 VGPR) FULLY unrolled -> register-resident. Per step:
// 64 global b128 h loads/lane (L2-deduped across waves), 128 MFMA, 32KB f32
// LDS gate exchange (swizzled), activation, u64 write-through h publish,
// per-block flag store + 64-lane poll (with s_sleep) + one acquire fence.
__global__ __launch_bounds__(256, 1) void k_scan(const u16* __restrict__ pre0, const u16* __restrict__ pre1,
                                                 const u16* __restrict__ whh0, const u16* __restrict__ whh1,
                                                 u16* __restrict__ o_out, u16* __restrict__ hbuf,
                                                 int* __restrict__ flags) {
  const int dir = blockIdx.y, blk = blockIdx.x;
  const u16* __restrict__ pre = dir ? pre1 : pre0;
  const u16* __restrict__ whh = dir ? whh1 : whh0;
  u16* hb = hbuf + dir * (2 * 64 * 512);
  int* myflags = flags + dir * 16;
  const int u0 = blk * 32;
  __shared__ __align__(16) float xch[64 * 128];  // 32KB, byte-addressed XOR swizzle
  const int tid = threadIdx.x, wv = tid >> 6, lane = tid & 63;
  const int l15 = lane & 15, q = lane >> 4;

  // persistent weight fragments: gate = wv, unit-tile ci, rows u0+ci*16+l15
  short8 sw[2][16];
#pragma unroll
  for (int ci = 0; ci < 2; ++ci)
#pragma unroll
    for (int kc = 0; kc < 16; ++kc)
      sw[ci][kc] = *(const short8a*)(whh + (long long)(wv * 512 + u0 + ci * 16 + l15) * 512 + kc * 32 + q * 8);

  // activation ownership: batch ab, unit octet u0+au .. +8
  const int ab = tid >> 2;
  const int au = (tid & 3) * 8;
  float c8[8];
#pragma unroll
  for (int j = 0; j < 8; ++j) c8[j] = 0.f;

  short8 pr[4], prn[4];
  {
    const int t0 = dir ? 255 : 0;
    const u16* pb = pre + (long long)(t0 * 64 + ab) * 2048 + u0 + au;
#pragma unroll
    for (int g = 0; g < 4; ++g) pr[g] = *(const short8a*)(pb + g * 512);
  }

  for (int tt = 0; tt < 256; ++tt) {
    const int t = dir ? (255 - tt) : tt;
    const u16* hrd = hb + (tt & 1) * 32768;
    u16* hwr = hb + ((tt + 1) & 1) * 32768;

    // per-bt base pointers; kc offsets fold into load immediates
    const u16* hl0 = hrd + l15 * 512 + q * 8;
    const u16* hl1 = hl0 + 16 * 512;
    const u16* hl2 = hl0 + 32 * 512;
    const u16* hl3 = hl0 + 48 * 512;

    float4_ acc[2][4];
#pragma unroll
    for (int ci = 0; ci < 2; ++ci)
#pragma unroll
      for (int bt = 0; bt < 4; ++bt) acc[ci][bt] = splat4(0.f);
#pragma unroll
    for (int kc = 0; kc < 16; ++kc) {
      const short8 a0 = *(const short8a*)(hl0 + kc * 32);
      const short8 a1 = *(const short8a*)(hl1 + kc * 32);
      const short8 a2 = *(const short8a*)(hl2 + kc * 32);
      const short8 a3 = *(const short8a*)(hl3 + kc * 32);
      acc[0][0] = MFMA16(sw[0][kc], a0, acc[0][0]);
      acc[0][1] = MFMA16(sw[0][kc], a1, acc[0][1]);
      acc[0][2] = MFMA16(sw[0][kc], a2, acc[0][2]);
      acc[0][3] = MFMA16(sw[0][kc], a3, acc[0][3]);
      acc[1][0] = MFMA16(sw[1][kc], a0, acc[1][0]);
      acc[1][1] = MFMA16(sw[1][kc], a1, acc[1][1]);
      acc[1][2] = MFMA16(sw[1][kc], a2, acc[1][2]);
      acc[1][3] = MFMA16(sw[1][kc], a3, acc[1][3]);
    }
    // gate exchange: write acc, swizzled (<=2-way)
#pragma unroll
    for (int ci = 0; ci < 2; ++ci)
#pragma unroll
      for (int bt = 0; bt < 4; ++bt) {
        const int b = bt * 16 + l15;
        const int lrb = wv * 32 + ci * 16 + q * 4;
        *(float4_*)((char*)xch + b * 512 + ((lrb * 4) ^ ((b & 7) << 6))) = acc[ci][bt];
      }
    __syncthreads();
    float4_ gv[4][2];
#pragma unroll
    for (int g = 0; g < 4; ++g)
#pragma unroll
      for (int h2 = 0; h2 < 2; ++h2) {
        const int lr = g * 32 + au + h2 * 4;
        gv[g][h2] = *(const float4_*)((const char*)xch + ab * 512 + ((lr * 4) ^ ((ab & 7) << 6)));
      }
    ull hv[2]; hv[0] = 0; hv[1] = 0;
#pragma unroll
    for (int j = 0; j < 8; ++j) {
      const float iv = gv[0][j >> 2][j & 3] + b2f((u16)pr[0][j]);
      const float fv = gv[1][j >> 2][j & 3] + b2f((u16)pr[1][j]);
      const float gg = gv[2][j >> 2][j & 3] + b2f((u16)pr[2][j]);
      const float ov = gv[3][j >> 2][j & 3] + b2f((u16)pr[3][j]);
      c8[j] = sigm(fv) * c8[j] + sigm(iv) * tanh_(gg);
      const float h = sigm(ov) * tanh_(c8[j]);
      hv[j >> 2] |= (ull)f2b(h) << (16 * (j & 3));
    }
#pragma unroll
    for (int p = 0; p < 2; ++p)
      __hip_atomic_store((ull*)(hwr + ab * 512 + u0 + au) + p, hv[p],
                         __ATOMIC_RELAXED, __HIP_MEMORY_SCOPE_AGENT);
    asm volatile("s_waitcnt vmcnt(0)" ::: "memory");  // h at coherent point
    __syncthreads();
    if (tid == 0)
      __hip_atomic_store(&myflags[blk], tt + 1, __ATOMIC_RELAXED, __HIP_MEMORY_SCOPE_AGENT);
    // overlap the wait: o_out store + next-step pre prefetch
    {
      ull* op = (ull*)(o_out + (long long)(t * 64 + ab) * 1024 + dir * 512 + u0 + au);
      op[0] = hv[0]; op[1] = hv[1];
    }
    {
      const int ttn = (tt < 255) ? tt + 1 : tt;
      const int tn = dir ? (255 - ttn) : ttn;
      const u16* pb = pre + (long long)(tn * 64 + ab) * 2048 + u0 + au;
#pragma unroll
      for (int g = 0; g < 4; ++g) prn[g] = *(const short8a*)(pb + g * 512);
    }
    if (tt != 255) {
      if (wv == 0) {
        int v;
        do {
          __builtin_amdgcn_s_sleep(1);
          v = __hip_atomic_load(&myflags[l15], __ATOMIC_RELAXED, __HIP_MEMORY_SCOPE_AGENT);
        } while (__all(v >= tt + 1) == 0);
      }
      __syncthreads();
      __builtin_amdgcn_fence(__ATOMIC_ACQUIRE, "agent");  // one inv; fresh h loads
    }
#pragma unroll
    for (int g = 0; g < 4; ++g) pr[g] = prn[g];
  }
}

// ---------------- launcher ----------------
static constexpr long long OFF_WT = 0;
static constexpr long long OFF_BIAS = 19660800;
static constexpr long long OFF_CAT = 19698944;
static constexpr long long OFF_EMB = 36476160;
static constexpr long long OFF_PRE = 44864768;
static constexpr long long OFF_O1 = 179082496;
static constexpr long long OFF_O2 = 212636928;
static constexpr long long OFF_SYNC = 246191360;
static constexpr long long SYNC_BYTES = 4096 + 524288;
static constexpr long long OFF_FLAG = OFF_SYNC + SYNC_BYTES;

extern "C" void kernel_launch(void* const* d_in, const int* in_sizes, int n_in,
                              void* d_out, int out_size, void* d_ws, size_t ws_size,
                              hipStream_t stream) {
  char* ws = (char*)d_ws;
  u16* wt = (u16*)(ws + OFF_WT);
  float* biasp = (float*)(ws + OFF_BIAS);
  u16* cat = (u16*)(ws + OFF_CAT);
  u16* emb = (u16*)(ws + OFF_EMB);
  u16* pre0 = (u16*)(ws + OFF_PRE);
  u16* pre1 = pre0 + (long long)16384 * 2048;
  u16* o1 = (u16*)(ws + OFF_O1);
  u16* o2 = (u16*)(ws + OFF_O2);
  int* cnt1 = (int*)(ws + OFF_SYNC);
  int* cnt2 = cnt1 + 512;
  u16* h1 = (u16*)(ws + OFF_SYNC + 4096);
  u16* h2 = h1 + 131072;
  int* flag = (int*)(ws + OFF_FLAG);

  hipMemsetAsync(ws + OFF_SYNC, 0, SYNC_BYTES, stream);
  k_detect<<<1, 256, 0, stream>>>((const unsigned*)d_in[30], flag);

  WSegs wsg;
  const int widx[14] = {4, 5, 8, 9, 12, 13, 16, 17, 20, 21, 24, 25, 28, 30};
  const int wdst[15] = {0, 32768, 98304, 131072, 196608, 720896, 1769472, 2293760,
                        3342336, 5439488, 6488064, 8585216, 9633792, 9764864, 9816064};
  const int wn[15] = {32768, 65536, 32768, 65536, 524288, 1048576, 524288, 1048576,
                      2097152, 1048576, 2097152, 1048576, 131072, 51200, 14336};
  for (int j = 0; j < 14; ++j) { wsg.src[j] = d_in[widx[j]]; wsg.dst[j] = wdst[j]; wsg.n[j] = wn[j]; }
  wsg.src[14] = nullptr; wsg.dst[14] = wdst[14]; wsg.n[14] = wn[14];
  k_convw<<<1200, 256, 0, stream>>>(wsg, wt, flag);

  BSegs bsg;
  const int ba[8] = {6, 10, 14, 18, 22, 26, 29, 31};
  const int bb[8] = {7, 11, 15, 19, 23, 27, -1, -1};
  const int bdst[8] = {0, 512, 1024, 3072, 5120, 7168, 9216, 9472};
  const int bn_[8] = {512, 512, 2048, 2048, 2048, 2048, 256, 50};
  const int bnp[8] = {512, 512, 2048, 2048, 2048, 2048, 256, 64};
  for (int j = 0; j < 8; ++j) {
    bsg.a[j] = d_in[ba[j]];
    bsg.b[j] = (bb[j] >= 0) ? d_in[bb[j]] : nullptr;
    bsg.dst[j] = bdst[j]; bsg.n[j] = bn_[j]; bsg.np[j] = bnp[j];
  }
  k_convb<<<40, 256, 0, stream>>>(bsg, biasp, flag);

  k_wordgather<<<16384, 128, 0, stream>>>((const int*)d_in[0], d_in[2], cat, flag);
  k_char<<<dim3(256, 2), 256, 0, stream>>>((const int*)d_in[1], d_in[3],
                                           wt + 0, wt + 32768, wt + 98304, wt + 131072,
                                           biasp + 0, biasp + 512, cat, flag);
  k_gemm<64, 64, 1, 0><<<dim3(256, 4), 256, 0, stream>>>(cat, wt + 9633792, biasp + 9216, emb, 256, 512, 256, flag);
  k_gemm<128, 256, 0, 0><<<dim3(128, 8), 256, 0, stream>>>(emb, wt + 196608, biasp + 1024, pre0, 2048, 256, 2048, flag);
  k_gemm<128, 256, 0, 0><<<dim3(128, 8), 256, 0, stream>>>(emb, wt + 1769472, biasp + 3072, pre1, 2048, 256, 2048, flag);
  k_scan<<<dim3(16, 2), 256, 0, stream>>>(pre0, pre1, wt + 720896, wt + 2293760, o1, h1, cnt1);
  k_gemm<128, 256, 0, 0><<<dim3(128, 8), 256, 0, stream>>>(o1, wt + 3342336, biasp + 5120, pre0, 2048, 1024, 2048, flag);
  k_gemm<128, 256, 0, 0><<<dim3(128, 8), 256, 0, stream>>>(o1, wt + 6488064, biasp + 7168, pre1, 2048, 1024, 2048, flag);
  k_scan<<<dim3(16, 2), 256, 0, stream>>>(pre0, pre1, wt + 5439488, wt + 8585216, o2, h2, cnt2);
  k_gemm<64, 64, 2, 1><<<dim3(256, 1), 256, 0, stream>>>(o2, wt + 9764864, biasp + 9472, d_out, 50, 1024, 50, flag);
}

// Round 5
// 6495.702 us; speedup vs baseline: 1.3768x; 1.0116x over previous
//
// BiLSTM tagger — MI355X. Round 5: pin scan weights in VGPRs.
// Change log vs R4: (1) sw fragments typed float4_ + opaque asm identity
// ("+v") after load -> compiler cannot rematerialize the loads inside the
// step loop (R4's VGPR_Count=124 proved it sank them -> 512KB/block/step L1
// re-stream). bit_cast to short8 at MFMA use. (2) gate-exchange swizzle
// (row&7)<<6 -> <<4: disjoint 4-bank groups on both write and read sides
// (R4 kept 7.3e6 conflict cycles). Everything else unchanged.
#include <hip/hip_runtime.h>

typedef unsigned short u16;
typedef unsigned long long ull;
typedef short short8 __attribute__((ext_vector_type(8)));
typedef float float4_ __attribute__((ext_vector_type(4)));
typedef short8 short8a __attribute__((may_alias));
typedef float4_ float4a __attribute__((may_alias));
typedef ull ulla __attribute__((may_alias));

#define MFMA16(a, b, c) __builtin_amdgcn_mfma_f32_16x16x32_bf16((a), (b), (c), 0, 0, 0)

static __device__ __forceinline__ float b2f(u16 v) { return __uint_as_float(((unsigned)v) << 16); }
static __device__ __forceinline__ u16 f2b(float f) {
  unsigned x = __float_as_uint(f);
  return (u16)((x + 0x7fffu + ((x >> 16) & 1u)) >> 16);
}
static __device__ __forceinline__ float ldv(const void* p, long long i, int isbf) {
  return isbf ? b2f(((const u16*)p)[i]) : ((const float*)p)[i];
}
static __device__ __forceinline__ float sigm(float x) { return 1.f / (1.f + __expf(-x)); }
static __device__ __forceinline__ float tanh_(float x) { return 1.f - 2.f / (__expf(2.f * x) + 1.f); }
static __device__ __forceinline__ float4_ splat4(float v) { float4_ r; r[0]=v; r[1]=v; r[2]=v; r[3]=v; return r; }
static __device__ __forceinline__ void keepv(float4_& v) { asm volatile("" : "+v"(v)); }

// ---------------- dtype detection (f32 vs bf16 input buffers) ----------------
__global__ __launch_bounds__(256) void k_detect(const unsigned* __restrict__ wtag, int* __restrict__ flag) {
  __shared__ int cs;
  if (threadIdx.x == 0) cs = 0;
  __syncthreads();
  int hits = 0;
  for (int i = threadIdx.x; i < 1024; i += 256) {
    unsigned b = (wtag[i] >> 8) & 0x7fu;
    hits += (b >= 0x36u && b <= 0x3fu) ? 1 : 0;
  }
  atomicAdd(&cs, hits);
  __syncthreads();
  if (threadIdx.x == 0) *flag = (cs > 512) ? 1 : 0;
}

// ---------------- weight conversion to bf16 workspace (x8 vectorized) ----------------
struct WSegs { const void* src[15]; int dst[15]; int n[15]; };
__global__ __launch_bounds__(256) void k_convw(WSegs s, u16* __restrict__ wt, const int* __restrict__ flagp) {
  const int isbf = *flagp;
  const long long total8 = 9830400 / 8;
  for (long long i8 = (long long)blockIdx.x * 256 + threadIdx.x; i8 < total8; i8 += (long long)gridDim.x * 256) {
    const long long i = i8 * 8;
    int k = 0;
#pragma unroll
    for (int j = 1; j < 15; ++j) if (i >= (long long)s.dst[j]) k = j;
    const long long loc = i - s.dst[k];
    short8 out;
    if (!s.src[k]) {
      for (int j = 0; j < 8; ++j) out[j] = 0;
    } else if (isbf) {
      out = *(const short8a*)((const u16*)s.src[k] + loc);
    } else {
      const float* fp = (const float*)s.src[k] + loc;
      const float4_ f0 = *(const float4a*)fp;
      const float4_ f1 = *(const float4a*)(fp + 4);
#pragma unroll
      for (int j = 0; j < 4; ++j) { out[j] = (short)f2b(f0[j]); out[j + 4] = (short)f2b(f1[j]); }
    }
    *(short8a*)(wt + i) = out;
  }
}

struct BSegs { const void* a[8]; const void* b[8]; int dst[8]; int n[8]; int np[8]; };
__global__ __launch_bounds__(256) void k_convb(BSegs s, float* __restrict__ bias, const int* __restrict__ flagp) {
  const int isbf = *flagp;
  for (int i = blockIdx.x * 256 + threadIdx.x; i < 9536; i += gridDim.x * 256) {
    int k = 0;
#pragma unroll
    for (int j = 1; j < 8; ++j) if (i >= s.dst[j]) k = j;
    const int loc = i - s.dst[k];
    float v = 0.f;
    if (loc < s.n[k]) {
      v = ldv(s.a[k], loc, isbf);
      if (s.b[k]) v += ldv(s.b[k], loc, isbf);
    }
    bias[i] = v;
  }
}

// ---------------- word embedding gather into cat[:,0:256] ----------------
__global__ __launch_bounds__(128) void k_wordgather(const int* __restrict__ sent, const void* __restrict__ wemb,
                                                    u16* __restrict__ cat, const int* __restrict__ flagp) {
  const int n = blockIdx.x;
  const int idx = sent[n];
  const int isbf = *flagp;
  for (int d = threadIdx.x; d < 256; d += 128)
    cat[(long long)n * 512 + d] = f2b(ldv(wemb, (long long)idx * 256 + d, isbf));
}

// ---------------- char biLSTM: 64 seqs/block, 16 steps, D=64 H=128 ----------------
__global__ __launch_bounds__(256) void k_char(const int* __restrict__ cs, const void* __restrict__ wchar,
                                              const u16* __restrict__ wihF, const u16* __restrict__ whhF,
                                              const u16* __restrict__ wihB, const u16* __restrict__ whhB,
                                              const float* __restrict__ biasF, const float* __restrict__ biasB,
                                              u16* __restrict__ cat, const int* __restrict__ flagp) {
  const int dir = blockIdx.y;
  const int nb = blockIdx.x;
  const u16* wih = dir ? wihB : wihF;
  const u16* whh = dir ? whhB : whhF;
  const float* bias = dir ? biasB : biasF;
  const int isbf = *flagp;
  __shared__ __align__(16) u16 xs[64][72];
  __shared__ __align__(16) u16 hs[64][136];
  const int tid = threadIdx.x, wv = tid >> 6, lane = tid & 63;
  for (int i = tid; i < 64 * 136; i += 256) ((u16*)hs)[i] = 0;
  float c[2][4][4];
#pragma unroll
  for (int a1 = 0; a1 < 2; ++a1)
#pragma unroll
    for (int a2 = 0; a2 < 4; ++a2)
#pragma unroll
      for (int a3 = 0; a3 < 4; ++a3) c[a1][a2][a3] = 0.f;

  for (int tt = 0; tt < 16; ++tt) {
    const int t = dir ? (15 - tt) : tt;
    {
      const int sid = tid >> 2, part = tid & 3;
      const int n = nb * 64 + sid;
      const int idx = cs[n * 16 + t];
#pragma unroll
      for (int q = 0; q < 16; ++q) {
        const int d2 = part * 16 + q;
        float v = 0.f;
        if (idx != 0) v = ldv(wchar, (long long)idx * 64 + d2, isbf);
        xs[sid][d2] = f2b(v);
      }
    }
    __syncthreads();
    float4_ acc[2][4][4];
#pragma unroll
    for (int ut = 0; ut < 2; ++ut)
#pragma unroll
      for (int g = 0; g < 4; ++g) {
        const float bv = bias[g * 128 + (wv + 4 * ut) * 16 + (lane & 15)];
#pragma unroll
        for (int rt = 0; rt < 4; ++rt) acc[ut][g][rt] = splat4(bv);
      }
#pragma unroll
    for (int kc = 0; kc < 6; ++kc) {
      short8 a[4];
      if (kc < 2) {
#pragma unroll
        for (int rt = 0; rt < 4; ++rt)
          a[rt] = *(const short8a*)&xs[rt * 16 + (lane & 15)][kc * 32 + (lane >> 4) * 8];
      } else {
#pragma unroll
        for (int rt = 0; rt < 4; ++rt)
          a[rt] = *(const short8a*)&hs[rt * 16 + (lane & 15)][(kc - 2) * 32 + (lane >> 4) * 8];
      }
#pragma unroll
      for (int ut = 0; ut < 2; ++ut)
#pragma unroll
        for (int g = 0; g < 4; ++g) {
          const int col = g * 128 + (wv + 4 * ut) * 16 + (lane & 15);
          short8 bfr;
          if (kc < 2) bfr = *(const short8a*)(wih + col * 64 + kc * 32 + (lane >> 4) * 8);
          else        bfr = *(const short8a*)(whh + col * 128 + (kc - 2) * 32 + (lane >> 4) * 8);
#pragma unroll
          for (int rt = 0; rt < 4; ++rt) acc[ut][g][rt] = MFMA16(a[rt], bfr, acc[ut][g][rt]);
        }
    }
    __syncthreads();
#pragma unroll
    for (int ut = 0; ut < 2; ++ut)
#pragma unroll
      for (int rt = 0; rt < 4; ++rt)
#pragma unroll
        for (int r = 0; r < 4; ++r) {
          const float iv = acc[ut][0][rt][r];
          const float fv = acc[ut][1][rt][r];
          const float gv = acc[ut][2][rt][r];
          const float ov = acc[ut][3][rt][r];
          float& cc = c[ut][rt][r];
          cc = sigm(fv) * cc + sigm(iv) * tanh_(gv);
          const float h = sigm(ov) * tanh_(cc);
          const int seq = rt * 16 + (lane >> 4) * 4 + r;
          const int u = (wv + 4 * ut) * 16 + (lane & 15);
          const u16 hv = f2b(h);
          hs[seq][u] = hv;
          if (tt == 15) cat[(long long)(nb * 64 + seq) * 512 + 256 + dir * 128 + u] = hv;
        }
  }
}

// ---------------- generic MFMA GEMM ----------------
template <int TM, int TN, int PERM, int OUTM>
__global__ __launch_bounds__(256) void k_gemm(const u16* __restrict__ A, const u16* __restrict__ Wt,
                                              const float* __restrict__ bias, void* __restrict__ Cout,
                                              const int N, const int K, const int ldc,
                                              const int* __restrict__ flagp) {
  constexpr int RT = TM / 16;
  constexpr int CPW = TN / 64;
  const int bm = blockIdx.x, bn = blockIdx.y;
  const int tid = threadIdx.x, wv = tid >> 6, lane = tid & 63;
  __shared__ __align__(16) u16 As[TM][72];
  float4_ acc[CPW][RT];
#pragma unroll
  for (int ci = 0; ci < CPW; ++ci)
#pragma unroll
    for (int rt = 0; rt < RT; ++rt) acc[ci][rt] = splat4(0.f);
  const int nk = K >> 6;
  for (int kc = 0; kc < nk; ++kc) {
    __syncthreads();
    for (int idx = tid; idx < TM * 4; idx += 256) {
      const int r = idx >> 2, sg = idx & 3;
      const u16* src = A + (long long)(bm * TM + r) * K + kc * 64 + sg * 16;
      *(short8a*)&As[r][sg * 16] = *(const short8a*)src;
      *(short8a*)&As[r][sg * 16 + 8] = *(const short8a*)(src + 8);
    }
    __syncthreads();
#pragma unroll
    for (int kk = 0; kk < 2; ++kk) {
      short8 af[RT];
#pragma unroll
      for (int rt = 0; rt < RT; ++rt)
        af[rt] = *(const short8a*)&As[rt * 16 + (lane & 15)][kk * 32 + (lane >> 4) * 8];
#pragma unroll
      for (int ci = 0; ci < CPW; ++ci) {
        const int ct = wv + ci * 4;
        const short8 bf = *(const short8a*)(Wt + (long long)(bn * TN + ct * 16 + (lane & 15)) * K +
                                            kc * 64 + kk * 32 + (lane >> 4) * 8);
#pragma unroll
        for (int rt = 0; rt < RT; ++rt) acc[ci][rt] = MFMA16(af[rt], bf, acc[ci][rt]);
      }
    }
  }
  const int isbf = (OUTM == 1) ? *flagp : 0;
#pragma unroll
  for (int ci = 0; ci < CPW; ++ci)
#pragma unroll
    for (int rt = 0; rt < RT; ++rt)
#pragma unroll
      for (int r = 0; r < 4; ++r) {
        const int row = bm * TM + rt * 16 + (lane >> 4) * 4 + r;
        const int col = bn * TN + (wv + ci * 4) * 16 + (lane & 15);
        if (col < N) {
          const float v = acc[ci][rt][r] + bias[col];
          long long orow;
          if (PERM == 0) orow = row;
          else if (PERM == 1) orow = (long long)(row & 255) * 64 + (row >> 8);
          else orow = (long long)(row & 63) * 256 + (row >> 6);
          if (OUTM == 0) ((u16*)Cout)[orow * ldc + col] = f2b(v);
          else if (isbf) ((u16*)Cout)[orow * ldc + col] = f2b(v);
          else ((float*)Cout)[orow * ldc + col] = v;
        }
      }
}

// ---------------- persistent LSTM scan (one layer, both dirs) ----------------
// grid (16, 2=dir). Block owns 32 hidden units. Wave w owns GATE w; weight
// fragments pinned in 128 VGPRs via opaque asm identity (compiler cannot
// rematerialize). Per step: 64 global b128 h loads/lane, 128 MFMA, 32KB f32
// LDS gate exchange (conflict-free swizzle), activation, u64 write-through h
// publish, per-block flag store + 64-lane poll (s_sleep) + one acquire fence.
__global__ __launch_bounds__(256, 1) void k_scan(const u16* __restrict__ pre0, const u16* __restrict__ pre1,
                                                 const u16* __restrict__ whh0, const u16* __restrict__ whh1,
                                                 u16* __restrict__ o_out, u16* __restrict__ hbuf,
                                                 int* __restrict__ flags) {
  const int dir = blockIdx.y, blk = blockIdx.x;
  const u16* __restrict__ pre = dir ? pre1 : pre0;
  const u16* __restrict__ whh = dir ? whh1 : whh0;
  u16* hb = hbuf + dir * (2 * 64 * 512);
  int* myflags = flags + dir * 16;
  const int u0 = blk * 32;
  __shared__ __align__(16) float xch[64 * 128];  // 32KB, byte-addressed XOR swizzle
  const int tid = threadIdx.x, wv = tid >> 6, lane = tid & 63;
  const int l15 = lane & 15, q = lane >> 4;

  // persistent weight fragments: gate = wv, unit-tile ci, rows u0+ci*16+l15.
  // float4_ + keepv => pinned in VGPRs for the whole kernel.
  float4_ swf[2][16];
#pragma unroll
  for (int ci = 0; ci < 2; ++ci)
#pragma unroll
    for (int kc = 0; kc < 16; ++kc) {
      swf[ci][kc] = *(const float4a*)(whh + (long long)(wv * 512 + u0 + ci * 16 + l15) * 512 + kc * 32 + q * 8);
      keepv(swf[ci][kc]);
    }

  // activation ownership: batch ab, unit octet u0+au .. +8
  const int ab = tid >> 2;
  const int au = (tid & 3) * 8;
  float c8[8];
#pragma unroll
  for (int j = 0; j < 8; ++j) c8[j] = 0.f;

  short8 pr[4], prn[4];
  {
    const int t0 = dir ? 255 : 0;
    const u16* pb = pre + (long long)(t0 * 64 + ab) * 2048 + u0 + au;
#pragma unroll
    for (int g = 0; g < 4; ++g) pr[g] = *(const short8a*)(pb + g * 512);
  }

  for (int tt = 0; tt < 256; ++tt) {
    const int t = dir ? (255 - tt) : tt;
    const u16* hrd = hb + (tt & 1) * 32768;
    u16* hwr = hb + ((tt + 1) & 1) * 32768;

    const u16* hl0 = hrd + l15 * 512 + q * 8;
    const u16* hl1 = hl0 + 16 * 512;
    const u16* hl2 = hl0 + 32 * 512;
    const u16* hl3 = hl0 + 48 * 512;

    float4_ acc[2][4];
#pragma unroll
    for (int ci = 0; ci < 2; ++ci)
#pragma unroll
      for (int bt = 0; bt < 4; ++bt) acc[ci][bt] = splat4(0.f);
#pragma unroll
    for (int kc = 0; kc < 16; ++kc) {
      const short8 w0 = __builtin_bit_cast(short8, swf[0][kc]);
      const short8 w1 = __builtin_bit_cast(short8, swf[1][kc]);
      const short8 a0 = *(const short8a*)(hl0 + kc * 32);
      const short8 a1 = *(const short8a*)(hl1 + kc * 32);
      const short8 a2 = *(const short8a*)(hl2 + kc * 32);
      const short8 a3 = *(const short8a*)(hl3 + kc * 32);
      acc[0][0] = MFMA16(w0, a0, acc[0][0]);
      acc[0][1] = MFMA16(w0, a1, acc[0][1]);
      acc[0][2] = MFMA16(w0, a2, acc[0][2]);
      acc[0][3] = MFMA16(w0, a3, acc[0][3]);
      acc[1][0] = MFMA16(w1, a0, acc[1][0]);
      acc[1][1] = MFMA16(w1, a1, acc[1][1]);
      acc[1][2] = MFMA16(w1, a2, acc[1][2]);
      acc[1][3] = MFMA16(w1, a3, acc[1][3]);
    }
    // gate exchange: swizzle ^((row&7)<<4) -> disjoint 4-bank groups, no conflicts
#pragma unroll
    for (int ci = 0; ci < 2; ++ci)
#pragma unroll
      for (int bt = 0; bt < 4; ++bt) {
        const int b = bt * 16 + l15;
        const int lrb = wv * 32 + ci * 16 + q * 4;
        *(float4a*)((char*)xch + b * 512 + ((lrb * 4) ^ ((b & 7) << 4))) = acc[ci][bt];
      }
    __syncthreads();
    float4_ gv[4][2];
#pragma unroll
    for (int g = 0; g < 4; ++g)
#pragma unroll
      for (int h2 = 0; h2 < 2; ++h2) {
        const int lr = g * 32 + au + h2 * 4;
        gv[g][h2] = *(const float4a*)((const char*)xch + ab * 512 + ((lr * 4) ^ ((ab & 7) << 4)));
      }
    ull hv[2]; hv[0] = 0; hv[1] = 0;
#pragma unroll
    for (int j = 0; j < 8; ++j) {
      const float iv = gv[0][j >> 2][j & 3] + b2f((u16)pr[0][j]);
      const float fv = gv[1][j >> 2][j & 3] + b2f((u16)pr[1][j]);
      const float gg = gv[2][j >> 2][j & 3] + b2f((u16)pr[2][j]);
      const float ov = gv[3][j >> 2][j & 3] + b2f((u16)pr[3][j]);
      c8[j] = sigm(fv) * c8[j] + sigm(iv) * tanh_(gg);
      const float h = sigm(ov) * tanh_(c8[j]);
      hv[j >> 2] |= (ull)f2b(h) << (16 * (j & 3));
    }
#pragma unroll
    for (int p = 0; p < 2; ++p)
      __hip_atomic_store((ull*)(hwr + ab * 512 + u0 + au) + p, hv[p],
                         __ATOMIC_RELAXED, __HIP_MEMORY_SCOPE_AGENT);
    asm volatile("s_waitcnt vmcnt(0)" ::: "memory");  // h at coherent point
    __syncthreads();
    if (tid == 0)
      __hip_atomic_store(&myflags[blk], tt + 1, __ATOMIC_RELAXED, __HIP_MEMORY_SCOPE_AGENT);
    // overlap the wait: o_out store + next-step pre prefetch
    {
      ull* op = (ull*)(o_out + (long long)(t * 64 + ab) * 1024 + dir * 512 + u0 + au);
      op[0] = hv[0]; op[1] = hv[1];
    }
    {
      const int ttn = (tt < 255) ? tt + 1 : tt;
      const int tn = dir ? (255 - ttn) : ttn;
      const u16* pb = pre + (long long)(tn * 64 + ab) * 2048 + u0 + au;
#pragma unroll
      for (int g = 0; g < 4; ++g) prn[g] = *(const short8a*)(pb + g * 512);
    }
    if (tt != 255) {
      if (wv == 0) {
        int v;
        do {
          __builtin_amdgcn_s_sleep(1);
          v = __hip_atomic_load(&myflags[l15], __ATOMIC_RELAXED, __HIP_MEMORY_SCOPE_AGENT);
        } while (__all(v >= tt + 1) == 0);
      }
      __syncthreads();
      __builtin_amdgcn_fence(__ATOMIC_ACQUIRE, "agent");  // one inv; fresh h loads
    }
#pragma unroll
    for (int g = 0; g < 4; ++g) pr[g] = prn[g];
  }
}

// ---------------- launcher ----------------
static constexpr long long OFF_WT = 0;
static constexpr long long OFF_BIAS = 19660800;
static constexpr long long OFF_CAT = 19698944;
static constexpr long long OFF_EMB = 36476160;
static constexpr long long OFF_PRE = 44864768;
static constexpr long long OFF_O1 = 179082496;
static constexpr long long OFF_O2 = 212636928;
static constexpr long long OFF_SYNC = 246191360;
static constexpr long long SYNC_BYTES = 4096 + 524288;
static constexpr long long OFF_FLAG = OFF_SYNC + SYNC_BYTES;

extern "C" void kernel_launch(void* const* d_in, const int* in_sizes, int n_in,
                              void* d_out, int out_size, void* d_ws, size_t ws_size,
                              hipStream_t stream) {
  char* ws = (char*)d_ws;
  u16* wt = (u16*)(ws + OFF_WT);
  float* biasp = (float*)(ws + OFF_BIAS);
  u16* cat = (u16*)(ws + OFF_CAT);
  u16* emb = (u16*)(ws + OFF_EMB);
  u16* pre0 = (u16*)(ws + OFF_PRE);
  u16* pre1 = pre0 + (long long)16384 * 2048;
  u16* o1 = (u16*)(ws + OFF_O1);
  u16* o2 = (u16*)(ws + OFF_O2);
  int* cnt1 = (int*)(ws + OFF_SYNC);
  int* cnt2 = cnt1 + 512;
  u16* h1 = (u16*)(ws + OFF_SYNC + 4096);
  u16* h2 = h1 + 131072;
  int* flag = (int*)(ws + OFF_FLAG);

  hipMemsetAsync(ws + OFF_SYNC, 0, SYNC_BYTES, stream);
  k_detect<<<1, 256, 0, stream>>>((const unsigned*)d_in[30], flag);

  WSegs wsg;
  const int widx[14] = {4, 5, 8, 9, 12, 13, 16, 17, 20, 21, 24, 25, 28, 30};
  const int wdst[15] = {0, 32768, 98304, 131072, 196608, 720896, 1769472, 2293760,
                        3342336, 5439488, 6488064, 8585216, 9633792, 9764864, 9816064};
  const int wn[15] = {32768, 65536, 32768, 65536, 524288, 1048576, 524288, 1048576,
                      2097152, 1048576, 2097152, 1048576, 131072, 51200, 14336};
  for (int j = 0; j < 14; ++j) { wsg.src[j] = d_in[widx[j]]; wsg.dst[j] = wdst[j]; wsg.n[j] = wn[j]; }
  wsg.src[14] = nullptr; wsg.dst[14] = wdst[14]; wsg.n[14] = wn[14];
  k_convw<<<1200, 256, 0, stream>>>(wsg, wt, flag);

  BSegs bsg;
  const int ba[8] = {6, 10, 14, 18, 22, 26, 29, 31};
  const int bb[8] = {7, 11, 15, 19, 23, 27, -1, -1};
  const int bdst[8] = {0, 512, 1024, 3072, 5120, 7168, 9216, 9472};
  const int bn_[8] = {512, 512, 2048, 2048, 2048, 2048, 256, 50};
  const int bnp[8] = {512, 512, 2048, 2048, 2048, 2048, 256, 64};
  for (int j = 0; j < 8; ++j) {
    bsg.a[j] = d_in[ba[j]];
    bsg.b[j] = (bb[j] >= 0) ? d_in[bb[j]] : nullptr;
    bsg.dst[j] = bdst[j]; bsg.n[j] = bn_[j]; bsg.np[j] = bnp[j];
  }
  k_convb<<<40, 256, 0, stream>>>(bsg, biasp, flag);

  k_wordgather<<<16384, 128, 0, stream>>>((const int*)d_in[0], d_in[2], cat, flag);
  k_char<<<dim3(256, 2), 256, 0, stream>>>((const int*)d_in[1], d_in[3],
                                           wt + 0, wt + 32768, wt + 98304, wt + 131072,
                                           biasp + 0, biasp + 512, cat, flag);
  k_gemm<64, 64, 1, 0><<<dim3(256, 4), 256, 0, stream>>>(cat, wt + 9633792, biasp + 9216, emb, 256, 512, 256, flag);
  k_gemm<128, 256, 0, 0><<<dim3(128, 8), 256, 0, stream>>>(emb, wt + 196608, biasp + 1024, pre0, 2048, 256, 2048, flag);
  k_gemm<128, 256, 0, 0><<<dim3(128, 8), 256, 0, stream>>>(emb, wt + 1769472, biasp + 3072, pre1, 2048, 256, 2048, flag);
  k_scan<<<dim3(16, 2), 256, 0, stream>>>(pre0, pre1, wt + 720896, wt + 2293760, o1, h1, cnt1);
  k_gemm<128, 256, 0, 0><<<dim3(128, 8), 256, 0, stream>>>(o1, wt + 3342336, biasp + 5120, pre0, 2048, 1024, 2048, flag);
  k_gemm<128, 256, 0, 0><<<dim3(128, 8), 256, 0, stream>>>(o1, wt + 6488064, biasp + 7168, pre1, 2048, 1024, 2048, flag);
  k_scan<<<dim3(16, 2), 256, 0, stream>>>(pre0, pre1, wt + 5439488, wt + 8585216, o2, h2, cnt2);
  k_gemm<64, 64, 2, 1><<<dim3(256, 1), 256, 0, stream>>>(o2, wt + 9764864, biasp + 9472, d_out, 50, 1024, 50, flag);
}